// Round 3
// baseline (489.102 us; speedup 1.0000x reference)
//
#include <hip/hip_runtime.h>
#include <stdint.h>
#include <stddef.h>

// Problem constants
#define IN_F   4096
#define OUT_F  14336
#define TOK    32

// Tiling
#define OTILE  64                 // output features per block (one per lane)
#define ISPLIT 8                  // grid.y split over the reduction dim
#define IBLK   (IN_F / ISPLIT)    // 512 i per block
#define ICHUNK 64                 // i per LDS stage (64 int32 = 256 B per row)
#define NCHUNK (IBLK / ICHUNK)    // 8

typedef const __attribute__((address_space(1))) void* gas_ptr;
typedef __attribute__((address_space(3))) void* las_ptr;

// Kernel 1: xsW[wv][i][t8] = x[8wv+t8][i] * scales[i]   ([4][4096][8] fp32, 512 KB)
// Per (wave, chunk) the qgemm x-operand is 512 contiguous floats.
// Also zeroes d_out (qgemm uses atomicAdd).
__global__ __launch_bounds__(256) void prep_kernel(
    const float* __restrict__ x, const float* __restrict__ scales,
    float* __restrict__ xsW, float* __restrict__ out)
{
    const int f = blockIdx.x * 256 + threadIdx.x;   // 0..131071 (grid 512)
    const int t = f >> 12;                          // 0..31 (coalesced x read)
    const int i = f & (IN_F - 1);
    const float v = x[f] * scales[i];
    // [wv][i][t&7]: scattered 32B-stride writes, 512 KB total, L2-absorbed
    xsW[(((size_t)(t >> 3) * IN_F) + i) * 8 + (t & 7)] = v;
    if (f < (OUT_F * TOK / 4)) {                    // zero 458752 floats
        ((float4*)out)[f] = make_float4(0.f, 0.f, 0.f, 0.f);
    }
}

// Main kernel: block = 4 waves; wave w owns tokens [8w, 8w+8); lane owns
// output feature o = o0+lane. Weights global->LDS via global_load_lds width=16
// (XOR-16 source swizzle so the by-o ds_read_b128 is 2-way-max on banks = free).
// x-side operand: wave-uniform VALUE but loaded through the VECTOR path
// (global_load_dwordx4, broadcast L1 hit). NOT readfirstlane'd — s_load would
// force lgkmcnt(0) drains (SMEM is out-of-order) that serialize the ds_reads.
__global__ __launch_bounds__(256, 5) void qgemm_kernel(
    const int* __restrict__ wgt, const float* __restrict__ xsW,
    float* __restrict__ out)
{
    __shared__ int lds[2][OTILE * ICHUNK];          // 2 x 16 KB
    const int lane = threadIdx.x & 63;
    const int wv   = threadIdx.x >> 6;              // divergent-typed: x path stays VMEM
    const int wvu  = __builtin_amdgcn_readfirstlane(wv); // scalar copy for LDS staging
    const int o0   = blockIdx.x * OTILE;
    const int ib0  = blockIdx.y * IBLK;
    const int lx   = lane & 15;

    float acc[8];
#pragma unroll
    for (int t = 0; t < 8; ++t) acc[t] = 0.f;

    // Stage chunk c of the 64x64 int32 weight tile into lds[buf].
    // One instr = 64 lanes x 16 B = 1 KB = 4 rows of 256 B (contiguous global).
    // LDS slot (row r, chunk16 pos lx) receives global chunk lx^(r&15).
    auto stage = [&](int buf, int c) {
#pragma unroll
        for (int k = 0; k < 4; ++k) {
            const int m = wvu * 4 + k;               // instr index 0..15 (scalar)
            const int r = m * 4 + (lane >> 4);       // row 0..63
            const int j = lx ^ (r & 15);             // swizzled source chunk
            const int* g = wgt + (size_t)(o0 + r) * IN_F
                               + (ib0 + c * ICHUNK) + (j << 2);
            int* l = &lds[buf][m * 256];             // +lane*16B added by HW
            __builtin_amdgcn_global_load_lds((gas_ptr)g, (las_ptr)l, 16, 0, 0);
        }
    };

    stage(0, 0);
    __syncthreads();

    int cur = 0;
    for (int c = 0; c < NCHUNK; ++c) {
        if (c + 1 < NCHUNK) stage(cur ^ 1, c + 1);   // prefetch next chunk

        const int* row = &lds[cur][lane * ICHUNK];
        // 512 contiguous floats for this (wave, chunk); wv divergent-typed ->
        // global_load_dwordx4 (vmcnt), never s_load.
        const float* xw = xsW + (((size_t)wv * IN_F) + ib0 + c * ICHUNK) * 8;
#pragma unroll
        for (int q = 0; q < 16; ++q) {
            // un-swizzle: global chunk q of my row sits at LDS chunk q^lx
            const int4 wq = *(const int4*)(row + ((q ^ lx) << 2));
            const float4* xp4 = (const float4*)(xw + q * 32); // 4 i x 8 t
            const float f0 = (float)wq.x;
            const float f1 = (float)wq.y;
            const float f2 = (float)wq.z;
            const float f3 = (float)wq.w;
            float4 a0 = xp4[0], a1 = xp4[1];   // i0: t0-3, t4-7
            float4 b0 = xp4[2], b1 = xp4[3];   // i1
            float4 c0 = xp4[4], c1 = xp4[5];   // i2
            float4 d0 = xp4[6], d1 = xp4[7];   // i3
            acc[0] = fmaf(f0, a0.x, acc[0]);
            acc[1] = fmaf(f0, a0.y, acc[1]);
            acc[2] = fmaf(f0, a0.z, acc[2]);
            acc[3] = fmaf(f0, a0.w, acc[3]);
            acc[4] = fmaf(f0, a1.x, acc[4]);
            acc[5] = fmaf(f0, a1.y, acc[5]);
            acc[6] = fmaf(f0, a1.z, acc[6]);
            acc[7] = fmaf(f0, a1.w, acc[7]);
            acc[0] = fmaf(f1, b0.x, acc[0]);
            acc[1] = fmaf(f1, b0.y, acc[1]);
            acc[2] = fmaf(f1, b0.z, acc[2]);
            acc[3] = fmaf(f1, b0.w, acc[3]);
            acc[4] = fmaf(f1, b1.x, acc[4]);
            acc[5] = fmaf(f1, b1.y, acc[5]);
            acc[6] = fmaf(f1, b1.z, acc[6]);
            acc[7] = fmaf(f1, b1.w, acc[7]);
            acc[0] = fmaf(f2, c0.x, acc[0]);
            acc[1] = fmaf(f2, c0.y, acc[1]);
            acc[2] = fmaf(f2, c0.z, acc[2]);
            acc[3] = fmaf(f2, c0.w, acc[3]);
            acc[4] = fmaf(f2, c1.x, acc[4]);
            acc[5] = fmaf(f2, c1.y, acc[5]);
            acc[6] = fmaf(f2, c1.z, acc[6]);
            acc[7] = fmaf(f2, c1.w, acc[7]);
            acc[0] = fmaf(f3, d0.x, acc[0]);
            acc[1] = fmaf(f3, d0.y, acc[1]);
            acc[2] = fmaf(f3, d0.z, acc[2]);
            acc[3] = fmaf(f3, d0.w, acc[3]);
            acc[4] = fmaf(f3, d1.x, acc[4]);
            acc[5] = fmaf(f3, d1.y, acc[5]);
            acc[6] = fmaf(f3, d1.z, acc[6]);
            acc[7] = fmaf(f3, d1.w, acc[7]);
        }
        __syncthreads();   // drains staging vmcnt; next iter reads cur^1
        cur ^= 1;
    }

    // Each (token, o) gets ISPLIT partial sums -> fp32 atomics (out zeroed by prep)
#pragma unroll
    for (int t = 0; t < 8; ++t) {
        atomicAdd(&out[(size_t)(wv * 8 + t) * OUT_F + o0 + lane], acc[t]);
    }
}

extern "C" void kernel_launch(void* const* d_in, const int* in_sizes, int n_in,
                              void* d_out, int out_size, void* d_ws, size_t ws_size,
                              hipStream_t stream)
{
    const float* x      = (const float*)d_in[0];   // [32, 4096] fp32
    const int*   wgt    = (const int*)d_in[1];     // [14336, 4096] int32 (int8 vals)
    const float* scales = (const float*)d_in[2];   // [4096] fp32
    float* out = (float*)d_out;                    // [32, 14336] fp32
    float* xsW = (float*)d_ws;                     // 512 KB scratch

    prep_kernel<<<dim3((TOK * IN_F) / 256), 256, 0, stream>>>(x, scales, xsW, out);

    dim3 grid(OUT_F / OTILE, ISPLIT);              // 224 x 8 = 1792 blocks
    qgemm_kernel<<<grid, 256, 0, stream>>>(wgt, xsW, out);
}

// Round 4
// 350.514 us; speedup vs baseline: 1.3954x; 1.3954x over previous
//
#include <hip/hip_runtime.h>
#include <stdint.h>
#include <stddef.h>

// Problem constants
#define IN_F   4096
#define OUT_F  14336
#define TOK    32

// Tiling
#define OTILE  64                 // output features per block (one per lane)
#define ISPLIT 16                 // grid.y split over the reduction dim
#define IBLK   (IN_F / ISPLIT)    // 256 i per block
#define ICHUNK 64                 // i per LDS weight stage (64 int32 = 256 B/row)
#define NCHUNK (IBLK / ICHUNK)    // 4

typedef const __attribute__((address_space(1))) void* gas_ptr;
typedef __attribute__((address_space(3))) void* las_ptr;

// Kernel 1: xsT[i*32 + t] = x[t][i] * scales[i]  ([4096][32] fp32, 512 KB).
// Also zeroes d_out (qgemm uses atomicAdd).
__global__ __launch_bounds__(256) void prep_kernel(
    const float* __restrict__ x, const float* __restrict__ scales,
    float* __restrict__ xsT, float* __restrict__ out)
{
    const int f = blockIdx.x * 256 + threadIdx.x;   // 0..131071 (grid 512)
    const int i = f >> 5;
    const int t = f & 31;
    // coalesced write; strided x read (512 KB total, L2-absorbed)
    xsT[f] = x[(size_t)t * IN_F + i] * scales[i];
    if (f < (OUT_F * TOK / 4)) {                    // zero 458752 floats
        ((float4*)out)[f] = make_float4(0.f, 0.f, 0.f, 0.f);
    }
}

// Main kernel: block = 4 waves; wave w owns tokens [8w,8w+8); lane owns output
// feature o0+lane. Weights: global->LDS via global_load_lds width=16 (XOR-16
// source swizzle -> by-o ds_read_b128 conflict-free), double-buffered.
// x: the block's whole [IBLK x 32] slice preloaded ONCE into LDS; inner loop
// reads it with wave-uniform-address ds_read_b128 (broadcast). Inner loop has
// ZERO global loads -> no vmcnt/lgkmcnt(0) serialization inside the loop.
__global__ __launch_bounds__(256, 4) void qgemm_kernel(
    const int* __restrict__ wgt, const float* __restrict__ xsT,
    float* __restrict__ out)
{
    __shared__ int   wtile[2][OTILE * ICHUNK];      // 2 x 16 KB weights
    __shared__ float xlds[IBLK * TOK];              // 32 KB x slice
    const int lane = threadIdx.x & 63;
    const int wv   = threadIdx.x >> 6;              // 0..3
    const int wvu  = __builtin_amdgcn_readfirstlane(wv);
    const int o0   = blockIdx.x * OTILE;
    const int ib0  = blockIdx.y * IBLK;
    const int lx   = lane & 15;

    float acc[8];
#pragma unroll
    for (int t = 0; t < 8; ++t) acc[t] = 0.f;

    // Stage weight chunk c (64 o x 64 i int32) into wtile[buf].
    // One instr = 64 lanes x 16 B = 1 KB = 4 rows. LDS slot (row r, pos lx)
    // receives global chunk lx^(r&15)  -> read-back is conflict-free.
    auto stage = [&](int buf, int c) {
#pragma unroll
        for (int k = 0; k < 4; ++k) {
            const int m = wvu * 4 + k;               // instr index 0..15
            const int r = m * 4 + (lane >> 4);       // row 0..63
            const int j = lx ^ (r & 15);             // swizzled source chunk
            const int* g = wgt + (size_t)(o0 + r) * IN_F
                               + (ib0 + c * ICHUNK) + (j << 2);
            int* l = &wtile[buf][m * 256];           // +lane*16B added by HW
            __builtin_amdgcn_global_load_lds((gas_ptr)g, (las_ptr)l, 16, 0, 0);
        }
    };

    stage(0, 0);

    // Preload x slice: 32 KB contiguous from xsT + ib0*32, coalesced float4.
    {
        const float4* src = (const float4*)(xsT + (size_t)ib0 * TOK);
        float4* dst = (float4*)xlds;
#pragma unroll
        for (int k = 0; k < 8; ++k)
            dst[k * 256 + threadIdx.x] = src[k * 256 + threadIdx.x];
    }
    __syncthreads();

    int cur = 0;
    for (int c = 0; c < NCHUNK; ++c) {
        if (c + 1 < NCHUNK) stage(cur ^ 1, c + 1);   // prefetch next chunk

        const int* row = &wtile[cur][lane * ICHUNK];
        const float* xc = xlds + (size_t)c * ICHUNK * TOK + wv * 8;
#pragma unroll
        for (int q = 0; q < 16; ++q) {
            // un-swizzle: global chunk q of my row sits at LDS chunk q^lx
            const int4 wq = *(const int4*)(row + ((q ^ lx) << 2));
            const float f0 = (float)wq.x;
            const float f1 = (float)wq.y;
            const float f2 = (float)wq.z;
            const float f3 = (float)wq.w;
            // x for 4 i x my wave's 8 t: uniform-address LDS reads (broadcast)
            const float* xq = xc + q * 4 * TOK;
            float4 a0 = *(const float4*)(xq);
            float4 a1 = *(const float4*)(xq + 4);
            float4 b0 = *(const float4*)(xq + TOK);
            float4 b1 = *(const float4*)(xq + TOK + 4);
            float4 c0 = *(const float4*)(xq + 2 * TOK);
            float4 c1 = *(const float4*)(xq + 2 * TOK + 4);
            float4 d0 = *(const float4*)(xq + 3 * TOK);
            float4 d1 = *(const float4*)(xq + 3 * TOK + 4);
            acc[0] = fmaf(f0, a0.x, acc[0]);
            acc[1] = fmaf(f0, a0.y, acc[1]);
            acc[2] = fmaf(f0, a0.z, acc[2]);
            acc[3] = fmaf(f0, a0.w, acc[3]);
            acc[4] = fmaf(f0, a1.x, acc[4]);
            acc[5] = fmaf(f0, a1.y, acc[5]);
            acc[6] = fmaf(f0, a1.z, acc[6]);
            acc[7] = fmaf(f0, a1.w, acc[7]);
            acc[0] = fmaf(f1, b0.x, acc[0]);
            acc[1] = fmaf(f1, b0.y, acc[1]);
            acc[2] = fmaf(f1, b0.z, acc[2]);
            acc[3] = fmaf(f1, b0.w, acc[3]);
            acc[4] = fmaf(f1, b1.x, acc[4]);
            acc[5] = fmaf(f1, b1.y, acc[5]);
            acc[6] = fmaf(f1, b1.z, acc[6]);
            acc[7] = fmaf(f1, b1.w, acc[7]);
            acc[0] = fmaf(f2, c0.x, acc[0]);
            acc[1] = fmaf(f2, c0.y, acc[1]);
            acc[2] = fmaf(f2, c0.z, acc[2]);
            acc[3] = fmaf(f2, c0.w, acc[3]);
            acc[4] = fmaf(f2, c1.x, acc[4]);
            acc[5] = fmaf(f2, c1.y, acc[5]);
            acc[6] = fmaf(f2, c1.z, acc[6]);
            acc[7] = fmaf(f2, c1.w, acc[7]);
            acc[0] = fmaf(f3, d0.x, acc[0]);
            acc[1] = fmaf(f3, d0.y, acc[1]);
            acc[2] = fmaf(f3, d0.z, acc[2]);
            acc[3] = fmaf(f3, d0.w, acc[3]);
            acc[4] = fmaf(f3, d1.x, acc[4]);
            acc[5] = fmaf(f3, d1.y, acc[5]);
            acc[6] = fmaf(f3, d1.z, acc[6]);
            acc[7] = fmaf(f3, d1.w, acc[7]);
        }
        __syncthreads();   // drains staging vmcnt; next iter reads cur^1
        cur ^= 1;
    }

    // Each (token, o) gets ISPLIT partial sums -> fp32 atomics (out zeroed by prep)
#pragma unroll
    for (int t = 0; t < 8; ++t) {
        atomicAdd(&out[(size_t)(wv * 8 + t) * OUT_F + o0 + lane], acc[t]);
    }
}

extern "C" void kernel_launch(void* const* d_in, const int* in_sizes, int n_in,
                              void* d_out, int out_size, void* d_ws, size_t ws_size,
                              hipStream_t stream)
{
    const float* x      = (const float*)d_in[0];   // [32, 4096] fp32
    const int*   wgt    = (const int*)d_in[1];     // [14336, 4096] int32 (int8 vals)
    const float* scales = (const float*)d_in[2];   // [4096] fp32
    float* out = (float*)d_out;                    // [32, 14336] fp32
    float* xsT = (float*)d_ws;                     // 512 KB scratch

    prep_kernel<<<dim3((TOK * IN_F) / 256), 256, 0, stream>>>(x, scales, xsT, out);

    dim3 grid(OUT_F / OTILE, ISPLIT);              // 224 x 16 = 3584 blocks
    qgemm_kernel<<<grid, 256, 0, stream>>>(wgt, xsT, out);
}

// Round 5
// 328.492 us; speedup vs baseline: 1.4889x; 1.0670x over previous
//
#include <hip/hip_runtime.h>
#include <stdint.h>
#include <stddef.h>

// Problem constants
#define IN_F   4096
#define OUT_F  14336
#define TOK    32

// Tiling
#define OTILE  64                 // output features per block (16 per wave)
#define ISPLIT 16                 // grid.y split over the reduction dim
#define IBLK   (IN_F / ISPLIT)    // 256 i per block
#define ICHUNK 64                 // i per LDS weight stage (64 int32 = 256 B/row)
#define NCHUNK (IBLK / ICHUNK)    // 4
#define KBPB   (IBLK / 32)        // 8 K-blocks (MFMA K=32) per block

typedef const __attribute__((address_space(1))) void* gas_ptr;
typedef __attribute__((address_space(3))) void* las_ptr;
typedef __attribute__((ext_vector_type(8))) short bf16x8;
typedef __attribute__((ext_vector_type(4))) float f32x4;

// prep: write xs = x*scales as bf16 in MFMA A-operand fragment order:
//   element (t,i): kb=i>>5, mt=t>>4, lane=((i>>3)&3)*16 + (t&15), j=i&7
//   int4 slot index = (kb*2+mt)*64 + lane   (j packed inside the int4)
// Each thread handles 8 consecutive i of one t -> exactly one int4 slot.
// Also zeroes d_out (qgemm accumulates with atomicAdd).
__global__ __launch_bounds__(256) void prep_kernel(
    const float* __restrict__ x, const float* __restrict__ scales,
    int4* __restrict__ xfrag, float* __restrict__ out)
{
    const int f = blockIdx.x * 256 + threadIdx.x;   // grid 512 -> 0..131071
    if (f < (TOK * IN_F / 8)) {                     // 16384 frag slots
        const int t  = f >> 9;                      // 0..31
        const int i8 = f & 511;                     // i = 8*i8 .. 8*i8+7
        const int kb = i8 >> 2;                     // i>>5
        const int kg = i8 & 3;                      // (i>>3)&3
        const float4* xp = (const float4*)(x + (size_t)t * IN_F + i8 * 8);
        const float4* sp = (const float4*)(scales + i8 * 8);
        float4 x0 = xp[0], x1 = xp[1];
        float4 s0 = sp[0], s1 = sp[1];
        float v[8] = { x0.x*s0.x, x0.y*s0.y, x0.z*s0.z, x0.w*s0.w,
                       x1.x*s1.x, x1.y*s1.y, x1.z*s1.z, x1.w*s1.w };
        uint32_t h[8];
#pragma unroll
        for (int j = 0; j < 8; ++j) {               // fp32 -> bf16 RNE
            uint32_t b = __float_as_uint(v[j]);
            b += 0x7fffu + ((b >> 16) & 1u);
            h[j] = b >> 16;
        }
        int4 d;
        d.x = (int)(h[0] | (h[1] << 16));
        d.y = (int)(h[2] | (h[3] << 16));
        d.z = (int)(h[4] | (h[5] << 16));
        d.w = (int)(h[6] | (h[7] << 16));
        xfrag[((kb * 2 + (t >> 4)) * 64) + kg * 16 + (t & 15)] = d;
    }
    if (f < (OUT_F * TOK / 4)) {                    // zero 458752 floats
        ((float4*)out)[f] = make_float4(0.f, 0.f, 0.f, 0.f);
    }
}

// Main kernel: 4 waves; wave w owns o-range [o0+16w, o0+16w+16), all 32 tokens.
// A (x, bf16) lives in 64 VGPRs loaded once. Weights stream global->LDS
// (R4's XOR-16 swizzled global_load_lds width=16, double-buffered), read back
// as 2x ds_read_b128 per lane (2-way banks = free), converted int->bf16
// in-register (EXACT: |w|<=127 fits bf16 mantissa), fed to
// mfma_f32_16x16x32_bf16. Inner loop: 4 b128 + 4 MFMA per chunk per wave.
__global__ __launch_bounds__(256, 4) void qgemm_kernel(
    const int* __restrict__ wgt, const int4* __restrict__ xfrag,
    float* __restrict__ out)
{
    __shared__ int wtile[2][OTILE * ICHUNK];        // 2 x 16 KB
    const int lane = threadIdx.x & 63;
    const int wv   = threadIdx.x >> 6;              // 0..3
    const int wvu  = __builtin_amdgcn_readfirstlane(wv);
    const int o0   = blockIdx.x * OTILE;
    const int ib0  = blockIdx.y * IBLK;
    const int lx   = lane & 15;                     // = n (B col / o offset)
    const int quad = lane >> 4;                     // B k-group

    // Load my A fragments once: 8 kb x 2 mt int4 = 64 VGPRs, fully coalesced.
    int4 a[KBPB][2];
#pragma unroll
    for (int kb = 0; kb < KBPB; ++kb)
#pragma unroll
        for (int mt = 0; mt < 2; ++mt)
            a[kb][mt] = xfrag[((blockIdx.y * KBPB + kb) * 2 + mt) * 64 + lane];

    // Stage weight chunk c (64 o x 64 i int32) into wtile[buf].
    // LDS slot (row r, chunk pos p) holds global chunk p^(r&15)  [R4-verified]
    auto stage = [&](int buf, int c) {
#pragma unroll
        for (int k = 0; k < 4; ++k) {
            const int m = wvu * 4 + k;               // instr index 0..15
            const int r = m * 4 + (lane >> 4);       // row 0..63
            const int j = lx ^ (r & 15);             // swizzled source chunk
            const int* g = wgt + (size_t)(o0 + r) * IN_F
                               + (ib0 + c * ICHUNK) + (j << 2);
            int* l = &wtile[buf][m * 256];           // +lane*16B added by HW
            __builtin_amdgcn_global_load_lds((gas_ptr)g, (las_ptr)l, 16, 0, 0);
        }
    };

    f32x4 acc[2] = { {0.f,0.f,0.f,0.f}, {0.f,0.f,0.f,0.f} };

    stage(0, 0);
    __syncthreads();

    int cur = 0;
#pragma unroll
    for (int c = 0; c < NCHUNK; ++c) {
        if (c + 1 < NCHUNK) stage(cur ^ 1, c + 1);   // prefetch next chunk

        // my B row: o = o0 + wvu*16 + lx  -> LDS row r with r&15 == lx
        const int* rowp = &wtile[cur][(wvu * 16 + lx) * ICHUNK];
#pragma unroll
        for (int kb2 = 0; kb2 < 2; ++kb2) {
            // k = kb2*32 + quad*8 + (0..7): global chunks g0, g0+1
            const int g0 = kb2 * 8 + quad * 2;
            const int4 w0 = *(const int4*)(rowp + ((g0 ^ lx) << 2));
            const int4 w1 = *(const int4*)(rowp + (((g0 + 1) ^ lx) << 2));
            // int -> bf16 exact (|w|<=127: fp32 bits below bit16 are zero)
            bf16x8 b;
            b[0] = (short)(__float_as_uint((float)w0.x) >> 16);
            b[1] = (short)(__float_as_uint((float)w0.y) >> 16);
            b[2] = (short)(__float_as_uint((float)w0.z) >> 16);
            b[3] = (short)(__float_as_uint((float)w0.w) >> 16);
            b[4] = (short)(__float_as_uint((float)w1.x) >> 16);
            b[5] = (short)(__float_as_uint((float)w1.y) >> 16);
            b[6] = (short)(__float_as_uint((float)w1.z) >> 16);
            b[7] = (short)(__float_as_uint((float)w1.w) >> 16);
            const int kbl = c * 2 + kb2;
            bf16x8 a0, a1;
            __builtin_memcpy(&a0, &a[kbl][0], 16);
            __builtin_memcpy(&a1, &a[kbl][1], 16);
            acc[0] = __builtin_amdgcn_mfma_f32_16x16x32_bf16(a0, b, acc[0], 0, 0, 0);
            acc[1] = __builtin_amdgcn_mfma_f32_16x16x32_bf16(a1, b, acc[1], 0, 0, 0);
        }
        __syncthreads();   // drains staging vmcnt; next iter reads cur^1
        cur ^= 1;
    }

    // C/D layout: D[row=quad*4+reg][col=lx]; t = mt*16 + quad*4 + reg,
    // o = o0 + wvu*16 + lx. ISPLIT partials -> fp32 atomics (out zeroed by prep).
#pragma unroll
    for (int mt = 0; mt < 2; ++mt)
#pragma unroll
        for (int reg = 0; reg < 4; ++reg) {
            const int t = mt * 16 + quad * 4 + reg;
            atomicAdd(&out[(size_t)t * OUT_F + o0 + wvu * 16 + lx], acc[mt][reg]);
        }
}

extern "C" void kernel_launch(void* const* d_in, const int* in_sizes, int n_in,
                              void* d_out, int out_size, void* d_ws, size_t ws_size,
                              hipStream_t stream)
{
    const float* x      = (const float*)d_in[0];   // [32, 4096] fp32
    const int*   wgt    = (const int*)d_in[1];     // [14336, 4096] int32 (int8 vals)
    const float* scales = (const float*)d_in[2];   // [4096] fp32
    float* out = (float*)d_out;                    // [32, 14336] fp32
    int4*  xfrag = (int4*)d_ws;                    // 256 KB scratch (A-frags)

    prep_kernel<<<dim3((TOK * IN_F) / 256), 256, 0, stream>>>(x, scales, xfrag, out);

    dim3 grid(OUT_F / OTILE, ISPLIT);              // 224 x 16 = 3584 blocks
    qgemm_kernel<<<grid, 256, 0, stream>>>(wgt, xfrag, out);
}